// Round 3
// baseline (155.430 us; speedup 1.0000x reference)
//
#include <hip/hip_runtime.h>
#include <math.h>

#define D_DIM 1024
#define TOKB  32            // tokens per block
#define NCH   32            // K-chunks of 32
// Wp layout (ushort bf16 bits): [ks 32][fb 12][pl 2][lane 64][j 8]
//   element (lane,j): k = ks*32 + (lane>>4)*8 + j ; f = fb*16 + (lane&15)
//   frag stride = 512 ushorts (1 KB); per-ks stride = 12*2*512 = 12288 ushorts

typedef short  bf16x8 __attribute__((ext_vector_type(8)));
typedef float  f32x4  __attribute__((ext_vector_type(4)));

__device__ __forceinline__ ushort f2bf(float f) {      // RTNE fp32 -> bf16 bits
  uint u = __float_as_uint(f);
  return (ushort)((u + 0x7fffu + ((u >> 16) & 1u)) >> 16);
}
__device__ __forceinline__ float bf2f(ushort h) {
  return __uint_as_float(((uint)h) << 16);
}
__device__ __forceinline__ float sigm(float v) {
  return 1.f / (1.f + expf(-v));
}

// Pack W_top/W_feat/W_gates^T into MFMA-B-fragment-ordered bf16 hi/lo planes.
// One thread per (ks, fb, lane, j-pair): 98304 threads, coalesced 64B reads.
__global__ __launch_bounds__(256) void pack_w_kernel(
    const float* __restrict__ Wt, const float* __restrict__ Wf,
    const float* __restrict__ Wg, ushort* __restrict__ Wp) {
  int gid = blockIdx.x * 256 + threadIdx.x;
  if (gid >= 32 * 12 * 64 * 4) return;
  int jp   = gid & 3;
  int t    = gid >> 2;
  int lane = t & 63;
  int t2   = t >> 6;
  int fb   = t2 % 12;
  int ks   = t2 / 12;
  int k0   = ks * 32 + ((lane >> 4) << 3) + jp * 2;
  int f    = fb * 16 + (lane & 15);
  float v0, v1;
  if (f < 64)       { v0 = Wt[k0 * 64 + f];            v1 = Wt[(k0 + 1) * 64 + f]; }
  else if (f < 128) { v0 = Wf[k0 * 64 + f - 64];       v1 = Wf[(k0 + 1) * 64 + f - 64]; }
  else              { v0 = Wg[(f - 128) * D_DIM + k0]; v1 = Wg[(f - 128) * D_DIM + k0 + 1]; }
  ushort h0 = f2bf(v0), h1 = f2bf(v1);
  ushort l0 = f2bf(v0 - bf2f(h0)), l1 = f2bf(v1 - bf2f(h1));
  size_t base = ((size_t)(ks * 12 + fb) * 2) * 512 + lane * 8 + jp * 2;
  *(uint*)(Wp + base)       = (uint)h0 | ((uint)h1 << 16);   // hi plane
  *(uint*)(Wp + base + 512) = (uint)l0 | ((uint)l1 << 16);   // lo plane
}

// 512 blocks x 256 threads (4 waves). Wave (wr,wc) = (wid>>1, wid&1):
//   16 tokens (wr) x 96 features (wc). No LDS / no syncthreads in main loop:
//   A from global x (in-reg hi/lo split), B fragments from L2-resident Wp.
__global__ __launch_bounds__(256, 2) void moe_gate_kernel(
    const float* __restrict__ x, const ushort* __restrict__ Wp,
    const float* __restrict__ b_top, const float* __restrict__ b_feat,
    const float* __restrict__ b_gates, const float* __restrict__ alpha,
    const int* __restrict__ nump, float* __restrict__ out) {
  __shared__ float L[32 * 196 + 192];          // logits [32][196] + biases
  float* bsm = L + 32 * 196;
  const int tid  = threadIdx.x;
  const int lane = tid & 63;
  const int wid  = tid >> 6;        // 0..3
  const int wr   = wid >> 1;        // token half
  const int wc   = wid & 1;         // feature half (96 feats)
  const int tok0 = blockIdx.x * TOKB;

  if (tid < 192)
    bsm[tid] = (tid < 64) ? b_top[tid]
             : (tid < 128) ? b_feat[tid - 64] : b_gates[tid - 128];

  // A source: lane reads x[tok0 + wr*16 + (lane&15)][c*32 + (lane>>4)*8 + 0..7]
  const float* xrow = x + (size_t)(tok0 + wr * 16 + (lane & 15)) * D_DIM
                        + ((lane >> 4) << 3);
  // B source: fragments for fb = wc*6 + fbl
  const ushort* wbase = Wp + (size_t)(wc * 6) * 1024 + lane * 8;

  f32x4 acc[6] = {};
  f32x4 xa = *(const f32x4*)(xrow);
  f32x4 xb = *(const f32x4*)(xrow + 4);

  for (int c = 0; c < NCH; ++c) {
    // in-register fp32 -> bf16 hi/lo split of this chunk's A fragment
    bf16x8 ah, al;
#pragma unroll
    for (int i = 0; i < 8; ++i) {
      float v = (i < 4) ? xa[i] : xb[i - 4];
      ushort h = f2bf(v);
      ah[i] = (short)h;
      al[i] = (short)f2bf(v - bf2f(h));
    }
    // prefetch next chunk's A (dup-reload of chunk 31 at the end: harmless)
    int cn = (c < NCH - 1) ? c + 1 : c;
    xa = *(const f32x4*)(xrow + cn * 32);
    xb = *(const f32x4*)(xrow + cn * 32 + 4);

    const ushort* wp = wbase + (size_t)c * 12288;
#pragma unroll
    for (int fbl = 0; fbl < 6; ++fbl) {
      bf16x8 bh = *(const bf16x8*)(wp + fbl * 1024);
      bf16x8 bl = *(const bf16x8*)(wp + fbl * 1024 + 512);
      acc[fbl] = __builtin_amdgcn_mfma_f32_16x16x32_bf16(ah, bh, acc[fbl], 0, 0, 0);
      acc[fbl] = __builtin_amdgcn_mfma_f32_16x16x32_bf16(al, bh, acc[fbl], 0, 0, 0);
      acc[fbl] = __builtin_amdgcn_mfma_f32_16x16x32_bf16(ah, bl, acc[fbl], 0, 0, 0);
    }
    // raw barrier (no vmcnt drain): keeps the 4 waves aligned so L1 catches
    // W reuse (wr pair) and x reuse (wc pair)
    __builtin_amdgcn_s_barrier();
  }

  __syncthreads();                  // bsm visibility (once, outside hot loop)
  // C/D layout (m89): token = wr*16 + (lane>>4)*4 + r, feat = wc*96 + fbl*16 + (lane&15)
#pragma unroll
  for (int fbl = 0; fbl < 6; ++fbl) {
    int f = wc * 96 + fbl * 16 + (lane & 15);
    int t = wr * 16 + ((lane >> 4) << 2);
    float bv = bsm[f];
#pragma unroll
    for (int r = 0; r < 4; ++r)
      L[(t + r) * 196 + f] = acc[fbl][r] + bv;
  }
  __syncthreads();

  // ---- parallel epilogue: 8 lanes per token (t = tid>>3, sub = tid&7),
  // each lane owns features f = sub + 8j, j=0..7
  {
    const int t   = tid >> 3;
    const int sub = tid & 7;
    const float* Lr = L + t * 196;
    float tp[8], ftv[8], gtv[8];
#pragma unroll
    for (int j = 0; j < 8; ++j) {
      int f = sub + 8 * j;
      tp[j]  = Lr[f];
      ftv[j] = Lr[64 + f];
      gtv[j] = sigm(Lr[128 + f]);
    }
    // dense branch: softmax(feat) . sigmoid(gates)
    float mf = ftv[0];
#pragma unroll
    for (int j = 1; j < 8; ++j) mf = fmaxf(mf, ftv[j]);
#pragma unroll
    for (int m = 1; m < 8; m <<= 1) mf = fmaxf(mf, __shfl_xor(mf, m, 8));
    float Zf = 0.f, Sf = 0.f;
#pragma unroll
    for (int j = 0; j < 8; ++j) {
      float e = expf(ftv[j] - mf);
      Zf += e;
      Sf = fmaf(gtv[j], e, Sf);
    }
#pragma unroll
    for (int m = 1; m < 8; m <<= 1) {
      Zf += __shfl_xor(Zf, m, 8);
      Sf += __shfl_xor(Sf, m, 8);
    }
    // top-k branch: cooperative argmax, lowest-index tie-break (= lax.top_k)
    int num = *nump;
    num = num < 1 ? 1 : (num > 64 ? 64 : num);
    uint sel8 = 0;
    float m0 = 0.f, Zt = 0.f, St = 0.f;
    for (int k = 0; k < num; ++k) {
      float bv = -3.4e38f; int bj = -1;
#pragma unroll
      for (int j = 0; j < 8; ++j)
        if (!((sel8 >> j) & 1u) && tp[j] > bv) { bv = tp[j]; bj = j; }
      int bf = (bj >= 0) ? (sub + 8 * bj) : (1 << 30);
#pragma unroll
      for (int m = 1; m < 8; m <<= 1) {
        float ov = __shfl_xor(bv, m, 8);
        int   of = __shfl_xor(bf, m, 8);
        if (ov > bv || (ov == bv && of < bf)) { bv = ov; bf = of; }
      }
      if (k == 0) m0 = bv;
      float e = expf(bv - m0);
      Zt += e;
      St = fmaf(sigm(Lr[128 + bf]), e, St);   // uniform addr per group: bcast
      if ((bf & 7) == sub) sel8 |= 1u << (bf >> 3);
    }
    if (sub == 0) {
      float a = sigm(alpha[0]);
      out[tok0 + t] = a * (St / Zt) + (1.f - a) * (Sf / Zf);
    }
  }
}

extern "C" void kernel_launch(void* const* d_in, const int* in_sizes, int n_in,
                              void* d_out, int out_size, void* d_ws, size_t ws_size,
                              hipStream_t stream) {
  const float* x       = (const float*)d_in[0];
  const float* W_top   = (const float*)d_in[1];
  const float* b_top   = (const float*)d_in[2];
  const float* W_feat  = (const float*)d_in[3];
  const float* b_feat  = (const float*)d_in[4];
  const float* W_gates = (const float*)d_in[5];
  const float* b_gates = (const float*)d_in[6];
  const float* alpha   = (const float*)d_in[7];
  const int*   nump    = (const int*)d_in[8];
  float*       out     = (float*)d_out;
  ushort*      Wp      = (ushort*)d_ws;      // 32*12*2*512 ushorts = 768 KB

  int n_tok = in_sizes[0] / D_DIM;           // 16384
  hipLaunchKernelGGL(pack_w_kernel, dim3(384), dim3(256), 0, stream,
                     W_top, W_feat, W_gates, Wp);
  hipLaunchKernelGGL(moe_gate_kernel, dim3(n_tok / TOKB), dim3(256), 0, stream,
                     x, Wp, b_top, b_feat, b_gates, alpha, nump, out);
}

// Round 4
// 141.046 us; speedup vs baseline: 1.1020x; 1.1020x over previous
//
#include <hip/hip_runtime.h>
#include <math.h>

#define D_DIM 1024
#define TOKB  32            // tokens per block
#define KCH   16            // chunks per K-half (chunk = 32 k), split-K by 2
// Wp layout (ushort bf16 bits): [ks 32][fb 12][pl 2][lane 64][j 8]
//   element (lane,j): k = ks*32 + (lane>>4)*8 + j ; f = fb*16 + (lane&15)
//   frag stride = 512 ushorts (1 KB); per-ks stride = 12*2*512 = 12288 ushorts

typedef short  bf16x8 __attribute__((ext_vector_type(8)));
typedef float  f32x4  __attribute__((ext_vector_type(4)));

__device__ __forceinline__ ushort f2bf(float f) {      // RTNE fp32 -> bf16 bits
  uint u = __float_as_uint(f);
  return (ushort)((u + 0x7fffu + ((u >> 16) & 1u)) >> 16);
}
__device__ __forceinline__ float bf2f(ushort h) {
  return __uint_as_float(((uint)h) << 16);
}
__device__ __forceinline__ float sigm(float v) {
  return 1.f / (1.f + expf(-v));
}
__device__ __forceinline__ void conv8(const f32x4 va, const f32x4 vb,
                                      bf16x8& ah, bf16x8& al) {
#pragma unroll
  for (int i = 0; i < 8; ++i) {
    float v = (i < 4) ? va[i] : vb[i - 4];
    ushort h = f2bf(v);
    ah[i] = (short)h;
    al[i] = (short)f2bf(v - bf2f(h));
  }
}

// Pack W_top/W_feat/W_gates^T into MFMA-B-fragment-ordered bf16 hi/lo planes.
__global__ __launch_bounds__(256) void pack_w_kernel(
    const float* __restrict__ Wt, const float* __restrict__ Wf,
    const float* __restrict__ Wg, ushort* __restrict__ Wp) {
  int gid = blockIdx.x * 256 + threadIdx.x;
  if (gid >= 32 * 12 * 64 * 4) return;
  int jp   = gid & 3;
  int t    = gid >> 2;
  int lane = t & 63;
  int t2   = t >> 6;
  int fb   = t2 % 12;
  int ks   = t2 / 12;
  int k0   = ks * 32 + ((lane >> 4) << 3) + jp * 2;
  int f    = fb * 16 + (lane & 15);
  float v0, v1;
  if (f < 64)       { v0 = Wt[k0 * 64 + f];            v1 = Wt[(k0 + 1) * 64 + f]; }
  else if (f < 128) { v0 = Wf[k0 * 64 + f - 64];       v1 = Wf[(k0 + 1) * 64 + f - 64]; }
  else              { v0 = Wg[(f - 128) * D_DIM + k0]; v1 = Wg[(f - 128) * D_DIM + k0 + 1]; }
  ushort h0 = f2bf(v0), h1 = f2bf(v1);
  ushort l0 = f2bf(v0 - bf2f(h0)), l1 = f2bf(v1 - bf2f(h1));
  size_t base = ((size_t)(ks * 12 + fb) * 2) * 512 + lane * 8 + jp * 2;
  *(uint*)(Wp + base)       = (uint)h0 | ((uint)h1 << 16);   // hi plane
  *(uint*)(Wp + base + 512) = (uint)l0 | ((uint)l1 << 16);   // lo plane
}

// 512 blocks x 256 threads (4 waves). Wave (kh,wc) = (wid>>1, wid&1):
//   32 tokens x 96 features x 512 K (split-K by 2). No barriers in main loop;
//   B fragments register-double-buffered from L2-resident Wp; A from global x.
__global__ __launch_bounds__(256, 2) void moe_gate_kernel(
    const float* __restrict__ x, const ushort* __restrict__ Wp,
    const float* __restrict__ b_top, const float* __restrict__ b_feat,
    const float* __restrict__ b_gates, const float* __restrict__ alpha,
    const int* __restrict__ nump, float* __restrict__ out) {
  __shared__ float L[32 * 196 + 192];          // logits [32][196] + biases
  float* bsm = L + 32 * 196;
  const int tid  = threadIdx.x;
  const int lane = tid & 63;
  const int wid  = tid >> 6;        // 0..3
  const int kh   = wid >> 1;        // K-half
  const int wc   = wid & 1;         // feature half (96 feats)
  const int tok0 = blockIdx.x * TOKB;

  if (tid < 192)
    bsm[tid] = (tid < 64) ? b_top[tid]
             : (tid < 128) ? b_feat[tid - 64] : b_gates[tid - 128];

  // A sources: 2 token frags; lane reads row tf*16+(lane&15), cols kh*512 + c*32 + (lane>>4)*8
  const float* xp0 = x + (size_t)(tok0 + (lane & 15)) * D_DIM + kh * 512 + ((lane >> 4) << 3);
  const float* xp1 = xp0 + (size_t)16 * D_DIM;
  // B source: fragments fb = wc*6 + fbl, chunks ks = kh*16 + c
  const ushort* wbase = Wp + (size_t)(kh * KCH) * 12288 + (size_t)(wc * 6) * 1024 + lane * 8;

  f32x4 acc[2][6] = {};
  bf16x8 bAh[6], bAl[6], bBh[6], bBl[6];
  f32x4 xA[4], xB[4];

#define LOADB(BH, BL, c) do {                                        \
    const ushort* wp_ = wbase + (size_t)(c) * 12288;                 \
    _Pragma("unroll")                                                \
    for (int q = 0; q < 6; ++q) {                                    \
      BH[q] = *(const bf16x8*)(wp_ + q * 1024);                      \
      BL[q] = *(const bf16x8*)(wp_ + q * 1024 + 512);                \
    } } while (0)
#define LOADX(XR, c) do {                                            \
    XR[0] = *(const f32x4*)(xp0 + (c) * 32);                         \
    XR[1] = *(const f32x4*)(xp0 + (c) * 32 + 4);                     \
    XR[2] = *(const f32x4*)(xp1 + (c) * 32);                         \
    XR[3] = *(const f32x4*)(xp1 + (c) * 32 + 4); } while (0)
#define COMPUTE(XR, BH, BL) do {                                     \
    bf16x8 ah0, al0, ah1, al1;                                       \
    conv8(XR[0], XR[1], ah0, al0);                                   \
    conv8(XR[2], XR[3], ah1, al1);                                   \
    _Pragma("unroll")                                                \
    for (int q = 0; q < 6; ++q) {                                    \
      acc[0][q] = __builtin_amdgcn_mfma_f32_16x16x32_bf16(ah0, BH[q], acc[0][q], 0, 0, 0); \
      acc[0][q] = __builtin_amdgcn_mfma_f32_16x16x32_bf16(al0, BH[q], acc[0][q], 0, 0, 0); \
      acc[0][q] = __builtin_amdgcn_mfma_f32_16x16x32_bf16(ah0, BL[q], acc[0][q], 0, 0, 0); \
      acc[1][q] = __builtin_amdgcn_mfma_f32_16x16x32_bf16(ah1, BH[q], acc[1][q], 0, 0, 0); \
      acc[1][q] = __builtin_amdgcn_mfma_f32_16x16x32_bf16(al1, BH[q], acc[1][q], 0, 0, 0); \
      acc[1][q] = __builtin_amdgcn_mfma_f32_16x16x32_bf16(ah1, BL[q], acc[1][q], 0, 0, 0); \
    } } while (0)

  // prologue: chunk 0 in flight
  LOADB(bAh, bAl, 0);
  LOADX(xA, 0);
  for (int c = 0; c < KCH; c += 2) {
    LOADB(bBh, bBl, c + 1);          // prefetch c+1 (covered by COMPUTE c)
    LOADX(xB, c + 1);
    COMPUTE(xA, bAh, bAl);
    if (c + 2 < KCH) {               // prefetch c+2 (covered by COMPUTE c+1)
      LOADB(bAh, bAl, c + 2);
      LOADX(xA, c + 2);
    }
    COMPUTE(xB, bBh, bBl);
  }
#undef LOADB
#undef LOADX
#undef COMPUTE

  __syncthreads();                  // bsm visibility; all waves past main loop
  // C/D layout (m89): token = tf*16 + (lane>>4)*4 + r, feat = wc*96 + fbl*16 + (lane&15)
  if (kh == 0) {
#pragma unroll
    for (int tf = 0; tf < 2; ++tf)
#pragma unroll
      for (int q = 0; q < 6; ++q) {
        int f = wc * 96 + q * 16 + (lane & 15);
        int t = tf * 16 + ((lane >> 4) << 2);
        float bv = bsm[f];
#pragma unroll
        for (int r = 0; r < 4; ++r)
          L[(t + r) * 196 + f] = acc[tf][q][r] + bv;
      }
  }
  __syncthreads();
  if (kh == 1) {
#pragma unroll
    for (int tf = 0; tf < 2; ++tf)
#pragma unroll
      for (int q = 0; q < 6; ++q) {
        int f = wc * 96 + q * 16 + (lane & 15);
        int t = tf * 16 + ((lane >> 4) << 2);
#pragma unroll
        for (int r = 0; r < 4; ++r)
          L[(t + r) * 196 + f] += acc[tf][q][r];
      }
  }
  __syncthreads();

  // ---- parallel epilogue: 8 lanes per token (t = tid>>3, sub = tid&7),
  // each lane owns features f = sub + 8j, j=0..7
  {
    const int t   = tid >> 3;
    const int sub = tid & 7;
    const float* Lr = L + t * 196;
    float tp[8], ftv[8], gtv[8];
#pragma unroll
    for (int j = 0; j < 8; ++j) {
      int f = sub + 8 * j;
      tp[j]  = Lr[f];
      ftv[j] = Lr[64 + f];
      gtv[j] = sigm(Lr[128 + f]);
    }
    // dense branch: softmax(feat) . sigmoid(gates)
    float mf = ftv[0];
#pragma unroll
    for (int j = 1; j < 8; ++j) mf = fmaxf(mf, ftv[j]);
#pragma unroll
    for (int m = 1; m < 8; m <<= 1) mf = fmaxf(mf, __shfl_xor(mf, m, 8));
    float Zf = 0.f, Sf = 0.f;
#pragma unroll
    for (int j = 0; j < 8; ++j) {
      float e = expf(ftv[j] - mf);
      Zf += e;
      Sf = fmaf(gtv[j], e, Sf);
    }
#pragma unroll
    for (int m = 1; m < 8; m <<= 1) {
      Zf += __shfl_xor(Zf, m, 8);
      Sf += __shfl_xor(Sf, m, 8);
    }
    // top-k branch: cooperative argmax, lowest-index tie-break (= lax.top_k)
    int num = *nump;
    num = num < 1 ? 1 : (num > 64 ? 64 : num);
    uint sel8 = 0;
    float m0 = 0.f, Zt = 0.f, St = 0.f;
    for (int k = 0; k < num; ++k) {
      float bv = -3.4e38f; int bj = -1;
#pragma unroll
      for (int j = 0; j < 8; ++j)
        if (!((sel8 >> j) & 1u) && tp[j] > bv) { bv = tp[j]; bj = j; }
      int bf = (bj >= 0) ? (sub + 8 * bj) : (1 << 30);
#pragma unroll
      for (int m = 1; m < 8; m <<= 1) {
        float ov = __shfl_xor(bv, m, 8);
        int   of = __shfl_xor(bf, m, 8);
        if (ov > bv || (ov == bv && of < bf)) { bv = ov; bf = of; }
      }
      if (k == 0) m0 = bv;
      float e = expf(bv - m0);
      Zt += e;
      St = fmaf(sigm(Lr[128 + bf]), e, St);   // uniform addr per group: bcast
      if ((bf & 7) == sub) sel8 |= 1u << (bf >> 3);
    }
    if (sub == 0) {
      float a = sigm(alpha[0]);
      out[tok0 + t] = a * (St / Zt) + (1.f - a) * (Sf / Zf);
    }
  }
}

extern "C" void kernel_launch(void* const* d_in, const int* in_sizes, int n_in,
                              void* d_out, int out_size, void* d_ws, size_t ws_size,
                              hipStream_t stream) {
  const float* x       = (const float*)d_in[0];
  const float* W_top   = (const float*)d_in[1];
  const float* b_top   = (const float*)d_in[2];
  const float* W_feat  = (const float*)d_in[3];
  const float* b_feat  = (const float*)d_in[4];
  const float* W_gates = (const float*)d_in[5];
  const float* b_gates = (const float*)d_in[6];
  const float* alpha   = (const float*)d_in[7];
  const int*   nump    = (const int*)d_in[8];
  float*       out     = (float*)d_out;
  ushort*      Wp      = (ushort*)d_ws;      // 32*12*2*512 ushorts = 768 KB

  int n_tok = in_sizes[0] / D_DIM;           // 16384
  hipLaunchKernelGGL(pack_w_kernel, dim3(384), dim3(256), 0, stream,
                     W_top, W_feat, W_gates, Wp);
  hipLaunchKernelGGL(moe_gate_kernel, dim3(n_tok / TOKB), dim3(256), 0, stream,
                     x, Wp, b_top, b_feat, b_gates, alpha, nump, out);
}